// Round 2
// baseline (3690.598 us; speedup 1.0000x reference)
//
#include <hip/hip_runtime.h>
#include <hip/hip_bf16.h>

// GraphConvolution on MI355X:
//   supT = (input @ W^T + b)^T  computed as  W @ input^T + b[row]  (NT GEMM, bf16 MFMA)
//   out_u = deg_u * (adj  @ sup_i)  = NT GEMM(A=adj_bf,  B=supT+8192 rows)
//   out_i = deg_i * (adjT @ sup_u)  = NT GEMM(A=adjT_bf, B=supT)
// GEMM: 256x256 tile, BK=64, 8 waves (2Mx4N), double-buffered LDS (128 KiB).
// Round-2 schedule: one-phase-ahead FRAGMENT prefetch so ds_read service of
// phase p+1 overlaps MFMA of phase p; only 2 barriers + 2 counted vmcnt per
// K-tile (mid: vmcnt(4) validates next-tile granule-0; end: vmcnt(0) g1).
// Workspace layout (>= 320 MiB):
//   [0,64Mi)    supT   2048x16384 bf16
//   [64,128Mi)  in_bf  16384x2048 bf16   -- reused by adj_bf after GEMM1
//   [128,136Mi) W_bf   2048x2048  bf16   -- dead after GEMM1
//   [64,192Mi)  adj_bf 8192x8192  bf16
//   [192,320Mi) adjT   8192x8192  bf16

typedef __bf16 bf16;
typedef bf16 bf16x4 __attribute__((ext_vector_type(4)));
typedef bf16 bf16x8 __attribute__((ext_vector_type(8)));
typedef float f32x4 __attribute__((ext_vector_type(4)));

#define AS1 __attribute__((address_space(1)))
#define AS3 __attribute__((address_space(3)))

// ---------------- fp32 -> bf16 straight convert (4 elems/thread) ----------------
__global__ __launch_bounds__(256) void k_cvt(const float* __restrict__ src,
                                             bf16* __restrict__ dst) {
  long i = ((long)blockIdx.x * 256 + threadIdx.x) * 4;
  float4 v = *(const float4*)(src + i);
  bf16x4 o;
  o.x = (bf16)v.x; o.y = (bf16)v.y; o.z = (bf16)v.z; o.w = (bf16)v.w;
  *(bf16x4*)(dst + i) = o;
}

// ---------------- adj: fused straight-cvt + transpose-cvt (reads adj ONCE) ------
__global__ __launch_bounds__(256) void k_adj_cvt(const float* __restrict__ src,
                                                 bf16* __restrict__ dst,
                                                 bf16* __restrict__ dstT, int n) {
  __shared__ float tile[64][65];
  const int bx = blockIdx.x * 64;  // source col block
  const int by = blockIdx.y * 64;  // source row block
  const int tx = threadIdx.x & 15, ty = threadIdx.x >> 4;
#pragma unroll
  for (int p = 0; p < 4; ++p) {
    const long r = by + p * 16 + ty;
    float4 v = *(const float4*)(src + r * n + bx + tx * 4);
    tile[p * 16 + ty][tx * 4 + 0] = v.x;
    tile[p * 16 + ty][tx * 4 + 1] = v.y;
    tile[p * 16 + ty][tx * 4 + 2] = v.z;
    tile[p * 16 + ty][tx * 4 + 3] = v.w;
    bf16x4 o;
    o.x = (bf16)v.x; o.y = (bf16)v.y; o.z = (bf16)v.z; o.w = (bf16)v.w;
    *(bf16x4*)(dst + r * n + bx + tx * 4) = o;
  }
  __syncthreads();
#pragma unroll
  for (int p = 0; p < 4; ++p) {
    bf16x4 o;
    o.x = (bf16)tile[tx * 4 + 0][p * 16 + ty];
    o.y = (bf16)tile[tx * 4 + 1][p * 16 + ty];
    o.z = (bf16)tile[tx * 4 + 2][p * 16 + ty];
    o.w = (bf16)tile[tx * 4 + 3][p * 16 + ty];
    *(bf16x4*)(dstT + (long)(bx + p * 16 + ty) * n + by + tx * 4) = o;
  }
}

// ---------------- NT bf16 GEMM, 256x256, fragment-pipelined ----------------
// C[m][n] = rowscale[m] * (sum_k A[m][k]*B[n][k]) + rowbias[m]
// 512 threads = 8 waves (wm=wave>>2 in {0,1}, wn=wave&3). Wave tile 128x64.
// A LDS: row-linear, granule g = tile rows {g*64..g*64+63, 128+g*64..}.
// B LDS: permuted so granule g = storage rows [g*128,(g+1)*128).
// XOR k-chunk swizzle folded into the GLOBAL address (LDS dest stays
// lane-contiguous as global_load_lds requires); reads swizzle by (row&7).

#define VM_WAIT4() asm volatile("s_waitcnt vmcnt(4)" ::: "memory")
#define VM_WAIT0() asm volatile("s_waitcnt vmcnt(0)" ::: "memory")
#define BARRIER() do { asm volatile("" ::: "memory"); \
                       __builtin_amdgcn_s_barrier(); \
                       asm volatile("" ::: "memory"); } while (0)

#define READ_AF(dst, base, mh) \
  _Pragma("unroll") for (int i = 0; i < 4; ++i) { \
    dst[i][0] = *(const bf16x8*)((base) + arow0 + (mh) * 4096 + i * 1024 + sw0); \
    dst[i][1] = *(const bf16x8*)((base) + arow0 + (mh) * 4096 + i * 1024 + sw1); \
  }

#define READ_BF(dst, base, nh) \
  _Pragma("unroll") for (int j = 0; j < 2; ++j) { \
    dst[j][0] = *(const bf16x8*)((base) + brow0 + (nh) * 8192 + j * 1024 + sw0); \
    dst[j][1] = *(const bf16x8*)((base) + brow0 + (nh) * 8192 + j * 1024 + sw1); \
  }

#define MFMA_PH(mh, nh, afx, bfx) \
  __builtin_amdgcn_s_setprio(1); \
  _Pragma("unroll") for (int i = 0; i < 4; ++i) \
  _Pragma("unroll") for (int j = 0; j < 2; ++j) \
  _Pragma("unroll") for (int ks = 0; ks < 2; ++ks) \
    acc[(mh) * 4 + i][(nh) * 2 + j] = __builtin_amdgcn_mfma_f32_16x16x32_bf16( \
        afx[i][ks], bfx[j][ks], acc[(mh) * 4 + i][(nh) * 2 + j], 0, 0, 0); \
  __builtin_amdgcn_s_setprio(0);

// Issue order: granule 0 (4 loads) then granule 1 (4 loads) -- vmcnt ledger.
#define STAGE_ALL(DA, DB, k0) do { \
  _Pragma("unroll") for (int g = 0; g < 2; ++g) { \
    _Pragma("unroll") for (int it = 0; it < 2; ++it) { \
      __builtin_amdgcn_global_load_lds((const AS1 void*)(Ab + aoff[g * 2 + it] + (k0)), \
                                       (AS3 void*)((DA) + alc[g * 2 + it]), 16, 0, 0); \
      __builtin_amdgcn_global_load_lds((const AS1 void*)(Bb + boff[g * 2 + it] + (k0)), \
                                       (AS3 void*)((DB) + blc[g * 2 + it]), 16, 0, 0); \
    } \
    __builtin_amdgcn_sched_barrier(0); \
  } \
} while (0)

// One K-tile.  Consumes af0/bfr0 (preloaded), pre-reads af0n/bfr0n for t+1.
#define TILE(t, CURA, CURB, NXA, NXB, af0, bfr0, af0n, bfr0n) do { \
  const bool pre = (t) + 1 < nt; \
  /* PH0: MFMA(0,0); read bfr1; issue all 8 stages for t+1 */ \
  READ_BF(bf1, CURB, 1); \
  if (pre) STAGE_ALL(NXA, NXB, ((t) + 1) << 6); \
  __builtin_amdgcn_sched_barrier(0); \
  MFMA_PH(0, 0, af0, bfr0); \
  /* PH1: read af1; MFMA(0,1) */ \
  READ_AF(af1, CURA, 1); \
  __builtin_amdgcn_sched_barrier(0); \
  MFMA_PH(0, 1, af0, bf1); \
  if (pre) { VM_WAIT4(); BARRIER(); } /* next-tile granule 0 valid */ \
  /* PH2: pre-read next bfr0; MFMA(1,0) */ \
  if (pre) { READ_BF(bfr0n, NXB, 0); } \
  __builtin_amdgcn_sched_barrier(0); \
  MFMA_PH(1, 0, af1, bfr0); \
  /* PH3: pre-read next af0; MFMA(1,1) */ \
  if (pre) { READ_AF(af0n, NXA, 0); } \
  __builtin_amdgcn_sched_barrier(0); \
  MFMA_PH(1, 1, af1, bf1); \
  if (pre) { VM_WAIT0(); BARRIER(); } /* next-tile granule 1 valid */ \
} while (0)

template <bool OUT_BF16>
__global__ __launch_bounds__(512, 2) void k_gemm_nt_pipe(
    const bf16* __restrict__ A, const bf16* __restrict__ B, void* __restrict__ Cout,
    int K, int lda, int ldb, int ldc,
    const float* __restrict__ rowscale, const float* __restrict__ rowbias) {
  __shared__ __align__(16) bf16 As[2][256 * 64];
  __shared__ __align__(16) bf16 Bs[2][256 * 64];
  const int tid = threadIdx.x;
  const int wave = tid >> 6, lane = tid & 63;
  const int quad = lane >> 4, l16 = lane & 15;
  const int wm = wave >> 2, wn = wave & 3;
  const int xm = l16 & 7;
  const int bm = blockIdx.y * 256, bn = blockIdx.x * 256;
  const bf16* Ab = A + (long)bm * lda;
  const bf16* Bb = B + (long)bn * ldb;

  // Fragment-read address components (element offsets into the LDS tiles).
  const int arow0 = wm * 8192 + l16 * 64;
  const int brow0 = wn * 2048 + l16 * 64;
  const int sw0 = ((0 + quad) ^ xm) << 3;
  const int sw1 = ((4 + quad) ^ xm) << 3;

  // Per-thread staging offsets: [g*2+it] -> global element offset + LDS offset.
  int aoff[4], alc[4], boff[4], blc[4];
#pragma unroll
  for (int g = 0; g < 2; ++g)
#pragma unroll
    for (int it = 0; it < 2; ++it) {
      const int u = it * 512 + tid;
      const int arow = ((u >> 9) << 7) + (g << 6) + ((u >> 3) & 63);
      aoff[g * 2 + it] = arow * lda + ((((u & 7) ^ (arow & 7)) << 3));
      alc[g * 2 + it] = (((u >> 9) << 10) + (g << 9) + (u & 511)) * 8;
      const int br = (g << 7) + (u >> 3);                               // storage row
      const int bp = (((u >> 8) & 3) << 6) + (g << 5) + ((u >> 3) & 31); // phys row
      boff[g * 2 + it] = bp * ldb + ((((u & 7) ^ (br & 7)) << 3));
      blc[g * 2 + it] = ((g << 10) + u) * 8;
    }

  f32x4 acc[8][4] = {};
  bf16x8 afP[4][2], afQ[4][2], af1[4][2];
  bf16x8 bfP[2][2], bfQ[2][2], bf1[2][2];

  bf16* const A0 = &As[0][0];
  bf16* const A1s = &As[1][0];
  bf16* const B0 = &Bs[0][0];
  bf16* const B1s = &Bs[1][0];

  // Prologue: stage tile 0, drain, pre-read PH0 fragments.
  STAGE_ALL(A0, B0, 0);
  VM_WAIT0();
  BARRIER();
  READ_AF(afP, A0, 0);
  READ_BF(bfP, B0, 0);

  const int nt = K >> 6;  // even for all shapes here (32 or 128)
  for (int t = 0; t < nt; t += 2) {
    TILE(t,     A0,  B0,  A1s, B1s, afP, bfP, afQ, bfQ);
    TILE(t + 1, A1s, B1s, A0,  B0,  afQ, bfQ, afP, bfP);
  }

  // Epilogue: C/D layout col=lane&15, row=quad*4+reg (guide §3, m89-verified).
#pragma unroll
  for (int mi = 0; mi < 8; ++mi) {
    const int r0 = bm + wm * 128 + mi * 16 + quad * 4;
    float sc[4], bi[4];
#pragma unroll
    for (int r = 0; r < 4; ++r) {
      sc[r] = rowscale ? rowscale[r0 + r] : 1.0f;
      bi[r] = rowbias ? rowbias[r0 + r] : 0.0f;
    }
#pragma unroll
    for (int j = 0; j < 4; ++j) {
      const int col = bn + wn * 64 + j * 16 + l16;
#pragma unroll
      for (int r = 0; r < 4; ++r) {
        float v = acc[mi][j][r] * sc[r] + bi[r];
        long idx = (long)(r0 + r) * ldc + col;
        if (OUT_BF16) ((bf16*)Cout)[idx] = (bf16)v;
        else          ((float*)Cout)[idx] = v;
      }
    }
  }
}

extern "C" void kernel_launch(void* const* d_in, const int* in_sizes, int n_in,
                              void* d_out, int out_size, void* d_ws, size_t ws_size,
                              hipStream_t stream) {
  const float* input  = (const float*)d_in[0];  // (16384, 2048)
  const float* adj    = (const float*)d_in[1];  // (8192, 8192)
  const float* degree = (const float*)d_in[2];  // (16384,)
  const float* W      = (const float*)d_in[3];  // (2048, 2048)
  const float* b      = (const float*)d_in[4];  // (2048,)
  float* out = (float*)d_out;                   // (16384, 2048) fp32

  char* ws = (char*)d_ws;
  bf16* supT   = (bf16*)(ws);                    // 2048 x 16384
  bf16* in_bf  = (bf16*)(ws + (64ULL  << 20));   // 16384 x 2048
  bf16* W_bf   = (bf16*)(ws + (128ULL << 20));   // 2048 x 2048
  bf16* adj_bf = (bf16*)(ws + (64ULL  << 20));   // 8192 x 8192 (reuses in_bf region)
  bf16* adjT   = (bf16*)(ws + (192ULL << 20));   // 8192 x 8192

  // Phase 0: convert GEMM1 operands.
  k_cvt<<<(16384 * 2048 / 4) / 256, 256, 0, stream>>>(input, in_bf);
  k_cvt<<<(2048 * 2048 / 4) / 256, 256, 0, stream>>>(W, W_bf);

  // Phase 1: supT = W @ input^T + b[row].  M=2048, N=16384, K=2048.
  k_gemm_nt_pipe<true><<<dim3(16384 / 256, 2048 / 256), 512, 0, stream>>>(
      W_bf, in_bf, supT, 2048, 2048, 2048, 16384, nullptr, b);

  // Phase 2: adj conversions, fused single pass over adj
  // (adj_bf overwrites in_bf -- GEMM1 already done).
  k_adj_cvt<<<dim3(128, 128), 256, 0, stream>>>(adj, adj_bf, adjT, 8192);

  // Phase 3: out_u = deg_u * (adj @ sup_i).  M=8192, N=2048, K=8192.
  k_gemm_nt_pipe<false><<<dim3(2048 / 256, 8192 / 256), 512, 0, stream>>>(
      adj_bf, supT + 8192, out, 8192, 8192, 16384, 2048, degree, nullptr);

  // Phase 4: out_i = deg_i * (adjT @ sup_u).
  k_gemm_nt_pipe<false><<<dim3(2048 / 256, 8192 / 256), 512, 0, stream>>>(
      adjT, supT, out + 8192LL * 2048, 8192, 8192, 16384, 2048, degree + 8192, nullptr);
}